// Round 1
// baseline (1766.904 us; speedup 1.0000x reference)
//
#include <hip/hip_runtime.h>
#include <math.h>

#define T_LEN 1024
#define C_DIM 2048
#define H_N   32
#define HEAD  64
#define BTC   (T_LEN * C_DIM)

typedef __attribute__((ext_vector_type(8))) __bf16 bf16x8;
typedef __attribute__((ext_vector_type(4))) float  f32x4;

// ---------------- elementwise cast kernels ----------------
__global__ void cast_bf16_k(const float* __restrict__ s, __bf16* __restrict__ d, int n) {
    int i = blockIdx.x * 256 + threadIdx.x;
    if (i < n) d[i] = (__bf16)s[i];
}
__global__ void tanh_cast_k(const float* __restrict__ s, __bf16* __restrict__ d, int n) {
    int i = blockIdx.x * 256 + threadIdx.x;
    if (i < n) d[i] = (__bf16)tanhf(s[i]);
}

// ---------------- transpose + cast: dst[c*R + r] = (bf16)src[r*C + c] ----------------
// All R,C used are multiples of 32. block (32,8), grid (C/32, R/32)
__global__ void transpose_cast_k(const float* __restrict__ src, __bf16* __restrict__ dst,
                                 int R, int C) {
    __shared__ float tile[32][33];
    int c0 = blockIdx.x * 32, r0 = blockIdx.y * 32;
    int tx = threadIdx.x, ty = threadIdx.y;
#pragma unroll
    for (int i = 0; i < 32; i += 8)
        tile[ty + i][tx] = src[(size_t)(r0 + ty + i) * C + c0 + tx];
    __syncthreads();
#pragma unroll
    for (int i = 0; i < 32; i += 8)
        dst[(size_t)(c0 + ty + i) * R + r0 + tx] = (__bf16)tile[tx][ty + i];
}

// ---------------- big GEMM: O(MxN) fp32 = A(MxK) bf16 * BT(NxK) bf16 ----------------
// block 256 = 4 waves; wave computes 16x64 tile; grid (M/64, N/64)
__global__ __launch_bounds__(256) void gemm_bt_16x64(
    const __bf16* __restrict__ A, const __bf16* __restrict__ BT,
    float* __restrict__ O, int M, int N, int K) {
    int lane = threadIdx.x & 63;
    int wv   = threadIdx.x >> 6;
    int m    = lane & 15;
    int q    = lane >> 4;
    int row0 = blockIdx.x * 64 + wv * 16;
    int col0 = blockIdx.y * 64;

    const __bf16* ap = A  + (size_t)(row0 + m) * K + q * 8;
    const __bf16* bp = BT + (size_t)(col0 + m) * K + q * 8;
    size_t bstride = (size_t)16 * K;

    f32x4 acc0 = {0.f,0.f,0.f,0.f}, acc1 = acc0, acc2 = acc0, acc3 = acc0;

    for (int k0 = 0; k0 < K; k0 += 32) {
        bf16x8 av = *(const bf16x8*)(ap + k0);
        bf16x8 b0 = *(const bf16x8*)(bp + k0);
        bf16x8 b1 = *(const bf16x8*)(bp + bstride + k0);
        bf16x8 b2 = *(const bf16x8*)(bp + 2 * bstride + k0);
        bf16x8 b3 = *(const bf16x8*)(bp + 3 * bstride + k0);
        acc0 = __builtin_amdgcn_mfma_f32_16x16x32_bf16(av, b0, acc0, 0, 0, 0);
        acc1 = __builtin_amdgcn_mfma_f32_16x16x32_bf16(av, b1, acc1, 0, 0, 0);
        acc2 = __builtin_amdgcn_mfma_f32_16x16x32_bf16(av, b2, acc2, 0, 0, 0);
        acc3 = __builtin_amdgcn_mfma_f32_16x16x32_bf16(av, b3, acc3, 0, 0, 0);
    }
    // C/D layout (verified m89): col = lane&15, row = (lane>>4)*4 + reg
    int orow = row0 + q * 4;
    int ocol = col0 + m;
#pragma unroll
    for (int i = 0; i < 4; i++) {
        O[(size_t)(orow + i) * N + ocol]      = acc0[i];
        O[(size_t)(orow + i) * N + ocol + 16] = acc1[i];
        O[(size_t)(orow + i) * N + ocol + 32] = acc2[i];
        O[(size_t)(orow + i) * N + ocol + 48] = acc3[i];
    }
}

// ---------------- small GEMM: one wave per 16x16 tile; grid (M/16, N/16), block 64 ----------------
__global__ __launch_bounds__(64) void gemm_bt_w16(
    const __bf16* __restrict__ A, const __bf16* __restrict__ BT,
    float* __restrict__ O, int M, int N, int K) {
    int lane = threadIdx.x & 63;
    int m = lane & 15, q = lane >> 4;
    int row0 = blockIdx.x * 16;
    int col0 = blockIdx.y * 16;
    const __bf16* ap = A  + (size_t)(row0 + m) * K + q * 8;
    const __bf16* bp = BT + (size_t)(col0 + m) * K + q * 8;
    f32x4 acc = {0.f,0.f,0.f,0.f};
    for (int k0 = 0; k0 < K; k0 += 32) {
        bf16x8 av = *(const bf16x8*)(ap + k0);
        bf16x8 bv = *(const bf16x8*)(bp + k0);
        acc = __builtin_amdgcn_mfma_f32_16x16x32_bf16(av, bv, acc, 0, 0, 0);
    }
    int orow = row0 + q * 4;
    int ocol = col0 + m;
#pragma unroll
    for (int i = 0; i < 4; i++)
        O[(size_t)(orow + i) * N + ocol] = acc[i];
}

// ---------------- prep: decay / gates / per-head kk normalize ----------------
// grid = T*H blocks, 64 threads. In-place: yw->dec, ya->a, yv->kk, k->k', v->v'
__global__ __launch_bounds__(64) void prep_k(
    float* __restrict__ kbuf, float* __restrict__ vbuf,
    const float* __restrict__ vfirst,
    float* __restrict__ ywb, float* __restrict__ yab, float* __restrict__ yvb,
    const float* __restrict__ w0, const float* __restrict__ a0,
    const float* __restrict__ v0, const float* __restrict__ k_k,
    const float* __restrict__ k_a) {
    int t = blockIdx.x >> 5;
    int h = blockIdx.x & 31;
    int n = threadIdx.x;
    int cc  = h * HEAD + n;
    int idx = t * C_DIM + cc;

    float kv = kbuf[idx];
    float vv = vbuf[idx];
    float wv = w0[cc] + ywb[idx];
    float wfin = -log1pf(expf(-wv)) - 0.6f;       // -softplus(-x) - 0.6
    float dec  = expf(-expf(wfin));
    float sv   = 1.f / (1.f + expf(-(v0[cc] + yvb[idx])));
    float vnew = fmaf(vfirst[idx] - vv, sv, vv);
    float av   = 1.f / (1.f + expf(-(a0[cc] + yab[idx])));
    float kkp  = kv * k_k[cc];
    float ss = kkp * kkp;
#pragma unroll
    for (int off = 32; off > 0; off >>= 1) ss += __shfl_xor(ss, off);
    float kkn  = kkp / fmaxf(sqrtf(ss), 1e-12f);
    float knew = kv * (1.f + (av - 1.f) * k_a[cc]);

    ywb[idx]  = dec;
    yab[idx]  = av;
    yvb[idx]  = kkn;
    kbuf[idx] = knew;
    vbuf[idx] = vnew;
}

// ---------------- sequential scan: 1 block per head, 256 threads ----------------
// thread = (row i = tid&63, chunk c = tid>>6 of 16 cols); state row in registers
__global__ __launch_bounds__(256) void scan_k(
    const float* __restrict__ dec, const float* __restrict__ kk,
    const float* __restrict__ asig, const float* __restrict__ kmat,
    const float* __restrict__ vmat, const float* __restrict__ rmat,
    const float* __restrict__ mask, float* __restrict__ out) {
    int h   = blockIdx.x;
    int tid = threadIdx.x;
    int i = tid & 63;
    int c = tid >> 6;

    float S[16];
#pragma unroll
    for (int jj = 0; jj < 16; jj++) S[jj] = 0.f;

    __shared__ float ld[384];    // [0]=dec [64]=kk [128]=a [192]=k [256]=v [320]=r
    __shared__ float psum[256];  // sa partials, layout i*4+c
    __shared__ float pout[256];  // out partials

    int o   = tid & 63;
    int sel = tid >> 6;

    for (int t = 0; t < T_LEN; t++) {
        int gbase = t * C_DIM + h * HEAD;
        // stage 6 x 64 floats
        float val;
        if      (sel == 0) val = dec [gbase + o];
        else if (sel == 1) val = kk  [gbase + o];
        else if (sel == 2) val = asig[gbase + o];
        else               val = kmat[gbase + o];
        ld[tid] = val;
        if (tid < 64)       ld[256 + tid] = vmat[gbase + tid];
        else if (tid < 128) ld[256 + tid] = rmat[gbase + (tid - 64)];
        __syncthreads();

        float m = mask[t];
        float dv[16], kkv[16], avv[16], kvv[16], rvv[16];
#pragma unroll
        for (int u = 0; u < 4; u++) {
            ((float4*)dv)[u]  = *((const float4*)&ld[  0 + c * 16] + u);
            ((float4*)kkv)[u] = *((const float4*)&ld[ 64 + c * 16] + u);
            ((float4*)avv)[u] = *((const float4*)&ld[128 + c * 16] + u);
            ((float4*)kvv)[u] = *((const float4*)&ld[192 + c * 16] + u);
            ((float4*)rvv)[u] = *((const float4*)&ld[320 + c * 16] + u);
        }
        // sa partial: sum_j S[i][j] * kk[j]  (a_in = -kk*m applied after reduce)
        float p = 0.f;
#pragma unroll
        for (int jj = 0; jj < 16; jj++) p += S[jj] * kkv[jj];
        psum[i * 4 + c] = p;
        __syncthreads();

        float4 sp = *(const float4*)&psum[i * 4];
        float sa = -m * (sp.x + sp.y + sp.z + sp.w);
        float vm = ld[256 + i] * m;
        float op = 0.f;
#pragma unroll
        for (int jj = 0; jj < 16; jj++) {
            float d   = dv[jj] * m + (1.f - m);
            float bb  = kkv[jj] * avv[jj] * m;
            float kjm = kvv[jj] * m;
            float s = S[jj] * d + sa * bb + vm * kjm;
            S[jj] = s;
            op += s * rvv[jj];
        }
        pout[i * 4 + c] = op;
        __syncthreads();
        if (c == 0) {
            float4 po = *(const float4*)&pout[i * 4];
            out[gbase + i] = po.x + po.y + po.z + po.w;
        }
    }
}

// ---------------- residual + cast + v_first passthrough ----------------
__global__ __launch_bounds__(64) void resid_k(
    const float* __restrict__ rbuf, const float* __restrict__ kbuf,
    const float* __restrict__ vbuf, const float* __restrict__ souts,
    const float* __restrict__ r_k, const float* __restrict__ vfirst,
    __bf16* __restrict__ ob, float* __restrict__ dout) {
    int t = blockIdx.x >> 5;
    int h = blockIdx.x & 31;
    int n = threadIdx.x;
    int idx = t * C_DIM + h * HEAD + n;
    float s = rbuf[idx] * kbuf[idx] * r_k[h * HEAD + n];
#pragma unroll
    for (int off = 32; off > 0; off >>= 1) s += __shfl_xor(s, off);
    float ov = souts[idx] + s * vbuf[idx];
    ob[idx] = (__bf16)ov;
    dout[BTC + idx] = vfirst[idx];   // second output: v_first unchanged
}

// ---------------- host launcher ----------------
extern "C" void kernel_launch(void* const* d_in, const int* in_sizes, int n_in,
                              void* d_out, int out_size, void* d_ws, size_t ws_size,
                              hipStream_t stream) {
    const float* x      = (const float*)d_in[0];
    const float* vfirst = (const float*)d_in[1];
    const float* amask  = (const float*)d_in[2];
    const float* w0 = (const float*)d_in[3];
    const float* w1 = (const float*)d_in[4];
    const float* w2 = (const float*)d_in[5];
    const float* a0 = (const float*)d_in[6];
    const float* a1 = (const float*)d_in[7];
    const float* a2 = (const float*)d_in[8];
    const float* v0 = (const float*)d_in[9];
    const float* v1 = (const float*)d_in[10];
    const float* v2 = (const float*)d_in[11];
    const float* k_k = (const float*)d_in[12];
    const float* k_a = (const float*)d_in[13];
    const float* r_k = (const float*)d_in[14];
    const float* Wr = (const float*)d_in[15];
    const float* Wk = (const float*)d_in[16];
    const float* Wv = (const float*)d_in[17];
    const float* Wo = (const float*)d_in[18];
    float* dout = (float*)d_out;

    char* wp = (char*)d_ws;
    auto alloc = [&](size_t bytes) -> void* {
        void* p = (void*)wp;
        wp += (bytes + 255) & ~(size_t)255;
        return p;
    };
    __bf16* xb  = (__bf16*)alloc((size_t)BTC * 2);
    __bf16* WrT = (__bf16*)alloc((size_t)C_DIM * C_DIM * 2);
    __bf16* WkT = (__bf16*)alloc((size_t)C_DIM * C_DIM * 2);
    __bf16* WvT = (__bf16*)alloc((size_t)C_DIM * C_DIM * 2);
    __bf16* WoT = (__bf16*)alloc((size_t)C_DIM * C_DIM * 2);
    __bf16* w1T = (__bf16*)alloc((size_t)96 * C_DIM * 2);
    __bf16* a1T = (__bf16*)alloc((size_t)96 * C_DIM * 2);
    __bf16* v1T = (__bf16*)alloc((size_t)64 * C_DIM * 2);
    __bf16* w2T = (__bf16*)alloc((size_t)C_DIM * 96 * 2);
    __bf16* a2T = (__bf16*)alloc((size_t)C_DIM * 96 * 2);
    __bf16* v2T = (__bf16*)alloc((size_t)C_DIM * 64 * 2);
    float*  rbuf = (float*)alloc((size_t)BTC * 4);
    float*  kbuf = (float*)alloc((size_t)BTC * 4);
    float*  vbuf = (float*)alloc((size_t)BTC * 4);
    float*  hw  = (float*)alloc((size_t)T_LEN * 96 * 4);
    float*  ha  = (float*)alloc((size_t)T_LEN * 96 * 4);
    float*  hv  = (float*)alloc((size_t)T_LEN * 64 * 4);
    __bf16* hwb = (__bf16*)alloc((size_t)T_LEN * 96 * 2);
    __bf16* hab = (__bf16*)alloc((size_t)T_LEN * 96 * 2);
    __bf16* hvb = (__bf16*)alloc((size_t)T_LEN * 64 * 2);
    float*  ywb = (float*)alloc((size_t)BTC * 4);   // -> dec
    float*  yab = (float*)alloc((size_t)BTC * 4);   // -> a
    float*  yvb = (float*)alloc((size_t)BTC * 4);   // -> kk
    float*  souts = (float*)alloc((size_t)BTC * 4);
    __bf16* ob  = (__bf16*)alloc((size_t)BTC * 2);

    // 1) cast x -> bf16
    cast_bf16_k<<<dim3(BTC / 256), 256, 0, stream>>>(x, xb, BTC);

    // 2) transpose+cast all weights (dst = C x R)
    dim3 tb(32, 8);
    transpose_cast_k<<<dim3(64, 64), tb, 0, stream>>>(Wr, WrT, C_DIM, C_DIM);
    transpose_cast_k<<<dim3(64, 64), tb, 0, stream>>>(Wk, WkT, C_DIM, C_DIM);
    transpose_cast_k<<<dim3(64, 64), tb, 0, stream>>>(Wv, WvT, C_DIM, C_DIM);
    transpose_cast_k<<<dim3(64, 64), tb, 0, stream>>>(Wo, WoT, C_DIM, C_DIM);
    transpose_cast_k<<<dim3(3, 64), tb, 0, stream>>>(w1, w1T, C_DIM, 96);
    transpose_cast_k<<<dim3(3, 64), tb, 0, stream>>>(a1, a1T, C_DIM, 96);
    transpose_cast_k<<<dim3(2, 64), tb, 0, stream>>>(v1, v1T, C_DIM, 64);
    transpose_cast_k<<<dim3(64, 3), tb, 0, stream>>>(w2, w2T, 96, C_DIM);
    transpose_cast_k<<<dim3(64, 3), tb, 0, stream>>>(a2, a2T, 96, C_DIM);
    transpose_cast_k<<<dim3(64, 2), tb, 0, stream>>>(v2, v2T, 64, C_DIM);

    // 3) big GEMMs: r, k, v
    gemm_bt_16x64<<<dim3(16, 32), 256, 0, stream>>>(xb, WrT, rbuf, T_LEN, C_DIM, C_DIM);
    gemm_bt_16x64<<<dim3(16, 32), 256, 0, stream>>>(xb, WkT, kbuf, T_LEN, C_DIM, C_DIM);
    gemm_bt_16x64<<<dim3(16, 32), 256, 0, stream>>>(xb, WvT, vbuf, T_LEN, C_DIM, C_DIM);

    // 4) LoRA first stage
    gemm_bt_w16<<<dim3(64, 6), 64, 0, stream>>>(xb, w1T, hw, T_LEN, 96, C_DIM);
    gemm_bt_w16<<<dim3(64, 6), 64, 0, stream>>>(xb, a1T, ha, T_LEN, 96, C_DIM);
    gemm_bt_w16<<<dim3(64, 4), 64, 0, stream>>>(xb, v1T, hv, T_LEN, 64, C_DIM);

    // 5) activations + cast
    tanh_cast_k<<<dim3((T_LEN * 96 + 255) / 256), 256, 0, stream>>>(hw, hwb, T_LEN * 96);
    cast_bf16_k<<<dim3((T_LEN * 96 + 255) / 256), 256, 0, stream>>>(ha, hab, T_LEN * 96);
    cast_bf16_k<<<dim3((T_LEN * 64 + 255) / 256), 256, 0, stream>>>(hv, hvb, T_LEN * 64);

    // 6) LoRA second stage
    gemm_bt_w16<<<dim3(64, 128), 64, 0, stream>>>(hwb, w2T, ywb, T_LEN, C_DIM, 96);
    gemm_bt_w16<<<dim3(64, 128), 64, 0, stream>>>(hab, a2T, yab, T_LEN, C_DIM, 96);
    gemm_bt_w16<<<dim3(64, 128), 64, 0, stream>>>(hvb, v2T, yvb, T_LEN, C_DIM, 64);

    // 7) prep: decay, gates, kk-normalize (in place)
    prep_k<<<dim3(T_LEN * H_N), 64, 0, stream>>>(kbuf, vbuf, vfirst, ywb, yab, yvb,
                                                 w0, a0, v0, k_k, k_a);

    // 8) sequential scan
    scan_k<<<dim3(H_N), 256, 0, stream>>>(ywb, yvb, yab, kbuf, vbuf, rbuf, amask, souts);

    // 9) residual + cast + v_first passthrough
    resid_k<<<dim3(T_LEN * H_N), 64, 0, stream>>>(rbuf, kbuf, vbuf, souts, r_k, vfirst,
                                                  ob, dout);

    // 10) final GEMM: dout[0:BTC] = ob @ Wo
    gemm_bt_16x64<<<dim3(16, 32), 256, 0, stream>>>(ob, WoT, dout, T_LEN, C_DIM, C_DIM);
}

// Round 2
// 992.437 us; speedup vs baseline: 1.7804x; 1.7804x over previous
//
#include <hip/hip_runtime.h>
#include <math.h>

#define T_LEN 1024
#define C_DIM 2048
#define H_N   32
#define HEAD  64
#define BTC   (T_LEN * C_DIM)

typedef __attribute__((ext_vector_type(8))) __bf16 bf16x8;
typedef __attribute__((ext_vector_type(4))) float  f32x4;

// ---------------- elementwise cast kernels ----------------
__global__ void cast_bf16_k(const float* __restrict__ s, __bf16* __restrict__ d, int n) {
    int i = blockIdx.x * 256 + threadIdx.x;
    if (i < n) d[i] = (__bf16)s[i];
}
__global__ void tanh_cast_k(const float* __restrict__ s, __bf16* __restrict__ d, int n) {
    int i = blockIdx.x * 256 + threadIdx.x;
    if (i < n) d[i] = (__bf16)tanhf(s[i]);
}

// ---------------- transpose + cast: dst[c*R + r] = (bf16)src[r*C + c] ----------------
__global__ void transpose_cast_k(const float* __restrict__ src, __bf16* __restrict__ dst,
                                 int R, int C) {
    __shared__ float tile[32][33];
    int c0 = blockIdx.x * 32, r0 = blockIdx.y * 32;
    int tx = threadIdx.x, ty = threadIdx.y;
#pragma unroll
    for (int i = 0; i < 32; i += 8)
        tile[ty + i][tx] = src[(size_t)(r0 + ty + i) * C + c0 + tx];
    __syncthreads();
#pragma unroll
    for (int i = 0; i < 32; i += 8)
        dst[(size_t)(c0 + ty + i) * R + r0 + tx] = (__bf16)tile[tx][ty + i];
}

// ---------------- big GEMM: O(MxN) fp32 = A(MxK) bf16 * BT(NxK) bf16 ----------------
__global__ __launch_bounds__(256) void gemm_bt_16x64(
    const __bf16* __restrict__ A, const __bf16* __restrict__ BT,
    float* __restrict__ O, int M, int N, int K) {
    int lane = threadIdx.x & 63;
    int wv   = threadIdx.x >> 6;
    int m    = lane & 15;
    int q    = lane >> 4;
    int row0 = blockIdx.x * 64 + wv * 16;
    int col0 = blockIdx.y * 64;

    const __bf16* ap = A  + (size_t)(row0 + m) * K + q * 8;
    const __bf16* bp = BT + (size_t)(col0 + m) * K + q * 8;
    size_t bstride = (size_t)16 * K;

    f32x4 acc0 = {0.f,0.f,0.f,0.f}, acc1 = acc0, acc2 = acc0, acc3 = acc0;

    for (int k0 = 0; k0 < K; k0 += 32) {
        bf16x8 av = *(const bf16x8*)(ap + k0);
        bf16x8 b0 = *(const bf16x8*)(bp + k0);
        bf16x8 b1 = *(const bf16x8*)(bp + bstride + k0);
        bf16x8 b2 = *(const bf16x8*)(bp + 2 * bstride + k0);
        bf16x8 b3 = *(const bf16x8*)(bp + 3 * bstride + k0);
        acc0 = __builtin_amdgcn_mfma_f32_16x16x32_bf16(av, b0, acc0, 0, 0, 0);
        acc1 = __builtin_amdgcn_mfma_f32_16x16x32_bf16(av, b1, acc1, 0, 0, 0);
        acc2 = __builtin_amdgcn_mfma_f32_16x16x32_bf16(av, b2, acc2, 0, 0, 0);
        acc3 = __builtin_amdgcn_mfma_f32_16x16x32_bf16(av, b3, acc3, 0, 0, 0);
    }
    int orow = row0 + q * 4;
    int ocol = col0 + m;
#pragma unroll
    for (int i = 0; i < 4; i++) {
        O[(size_t)(orow + i) * N + ocol]      = acc0[i];
        O[(size_t)(orow + i) * N + ocol + 16] = acc1[i];
        O[(size_t)(orow + i) * N + ocol + 32] = acc2[i];
        O[(size_t)(orow + i) * N + ocol + 48] = acc3[i];
    }
}

// ---------------- small GEMM: one wave per 16x16 tile ----------------
__global__ __launch_bounds__(64) void gemm_bt_w16(
    const __bf16* __restrict__ A, const __bf16* __restrict__ BT,
    float* __restrict__ O, int M, int N, int K) {
    int lane = threadIdx.x & 63;
    int m = lane & 15, q = lane >> 4;
    int row0 = blockIdx.x * 16;
    int col0 = blockIdx.y * 16;
    const __bf16* ap = A  + (size_t)(row0 + m) * K + q * 8;
    const __bf16* bp = BT + (size_t)(col0 + m) * K + q * 8;
    f32x4 acc = {0.f,0.f,0.f,0.f};
    for (int k0 = 0; k0 < K; k0 += 32) {
        bf16x8 av = *(const bf16x8*)(ap + k0);
        bf16x8 bv = *(const bf16x8*)(bp + k0);
        acc = __builtin_amdgcn_mfma_f32_16x16x32_bf16(av, bv, acc, 0, 0, 0);
    }
    int orow = row0 + q * 4;
    int ocol = col0 + m;
#pragma unroll
    for (int i = 0; i < 4; i++)
        O[(size_t)(orow + i) * N + ocol] = acc[i];
}

// ---------------- prep: decay / gates / kk-normalize + mask folding ----------------
// grid = T*H blocks, 64 threads.
// Writes fused scan inputs: ywb<-d_eff, yvb<-a_eff(-kk*m), yab<-b_eff(kk*a*m),
// sck<-k_new*m, scv<-v_new*m. Also kbuf<-k_new, vbuf<-v_new (unmasked, for resid).
__global__ __launch_bounds__(64) void prep_k(
    float* __restrict__ kbuf, float* __restrict__ vbuf,
    const float* __restrict__ vfirst,
    float* __restrict__ ywb, float* __restrict__ yab, float* __restrict__ yvb,
    float* __restrict__ sck, float* __restrict__ scv,
    const float* __restrict__ w0, const float* __restrict__ a0,
    const float* __restrict__ v0, const float* __restrict__ k_k,
    const float* __restrict__ k_a, const float* __restrict__ amask) {
    int t = blockIdx.x >> 5;
    int h = blockIdx.x & 31;
    int n = threadIdx.x;
    int cc  = h * HEAD + n;
    int idx = t * C_DIM + cc;
    float m = amask[t];

    float kv = kbuf[idx];
    float vv = vbuf[idx];
    float wv = w0[cc] + ywb[idx];
    float wfin = -log1pf(expf(-wv)) - 0.6f;       // -softplus(-x) - 0.6
    float dec  = expf(-expf(wfin));
    float sv   = 1.f / (1.f + expf(-(v0[cc] + yvb[idx])));
    float vnew = fmaf(vfirst[idx] - vv, sv, vv);
    float av   = 1.f / (1.f + expf(-(a0[cc] + yab[idx])));
    float kkp  = kv * k_k[cc];
    float ss = kkp * kkp;
#pragma unroll
    for (int off = 32; off > 0; off >>= 1) ss += __shfl_xor(ss, off);
    float kkn  = kkp / fmaxf(sqrtf(ss), 1e-12f);
    float knew = kv * (1.f + (av - 1.f) * k_a[cc]);

    ywb[idx]  = dec * m + (1.f - m);   // d_eff
    yvb[idx]  = -kkn * m;              // a_eff
    yab[idx]  = kkn * av * m;          // b_eff
    sck[idx]  = knew * m;              // k_eff
    scv[idx]  = vnew * m;              // v_eff
    kbuf[idx] = knew;                  // unmasked, for residual
    vbuf[idx] = vnew;                  // unmasked, for residual
}

// ---------------- sequential scan: 256 single-wave blocks ----------------
// block = (head h, row-group g): 8 rows of the state. lane = (r<<3)|c:
// lane holds S[g*8+r][c*8 .. c*8+8). No LDS, no barriers; shfl_xor reduces
// over the 8 col-chunks. Next timestep prefetched into registers.
struct StepRegs { float d[8], a[8], b[8], k[8], r[8]; float v; };

__device__ inline void load_step(StepRegs& s,
    const float* __restrict__ dm, const float* __restrict__ am,
    const float* __restrict__ bm, const float* __restrict__ km,
    const float* __restrict__ vm, const float* __restrict__ rm,
    int off, int jb, int row) {
    *(float4*)&s.d[0] = *(const float4*)(dm + off + jb);
    *(float4*)&s.d[4] = *(const float4*)(dm + off + jb + 4);
    *(float4*)&s.a[0] = *(const float4*)(am + off + jb);
    *(float4*)&s.a[4] = *(const float4*)(am + off + jb + 4);
    *(float4*)&s.b[0] = *(const float4*)(bm + off + jb);
    *(float4*)&s.b[4] = *(const float4*)(bm + off + jb + 4);
    *(float4*)&s.k[0] = *(const float4*)(km + off + jb);
    *(float4*)&s.k[4] = *(const float4*)(km + off + jb + 4);
    *(float4*)&s.r[0] = *(const float4*)(rm + off + jb);
    *(float4*)&s.r[4] = *(const float4*)(rm + off + jb + 4);
    s.v = vm[off + row];
}

__global__ __launch_bounds__(64) void scan_k(
    const float* __restrict__ dm, const float* __restrict__ am,
    const float* __restrict__ bm, const float* __restrict__ km,
    const float* __restrict__ vm, const float* __restrict__ rm,
    float* __restrict__ out) {
    int h = blockIdx.x >> 3;
    int g = blockIdx.x & 7;
    int lane = threadIdx.x;
    int r = lane >> 3;
    int c = lane & 7;
    int row = g * 8 + r;
    int jb  = c * 8;

    float S[8];
#pragma unroll
    for (int j = 0; j < 8; j++) S[j] = 0.f;

    int off = h * HEAD;
    StepRegs cur, nxt;
    load_step(cur, dm, am, bm, km, vm, rm, off, jb, row);

    for (int t = 0; t < T_LEN; t++) {
        int offn = (t + 1 < T_LEN) ? off + C_DIM : off;
        load_step(nxt, dm, am, bm, km, vm, rm, offn, jb, row);

        // sa partial: sum_j S[j] * a[j], reduce over 8 col-chunks
        float p = 0.f;
#pragma unroll
        for (int j = 0; j < 8; j++) p += S[j] * cur.a[j];
        p += __shfl_xor(p, 1);
        p += __shfl_xor(p, 2);
        p += __shfl_xor(p, 4);
        float sa = p;

        // update + out partial
        float op = 0.f;
#pragma unroll
        for (int j = 0; j < 8; j++) {
            float s = fmaf(cur.d[j], S[j], fmaf(sa, cur.b[j], cur.v * cur.k[j]));
            S[j] = s;
            op = fmaf(s, cur.r[j], op);
        }
        op += __shfl_xor(op, 1);
        op += __shfl_xor(op, 2);
        op += __shfl_xor(op, 4);
        if (c == 0) out[off + row] = op;

        cur = nxt;
        off += C_DIM;
    }
}

// ---------------- residual + cast + v_first passthrough ----------------
__global__ __launch_bounds__(64) void resid_k(
    const float* __restrict__ rbuf, const float* __restrict__ kbuf,
    const float* __restrict__ vbuf, const float* __restrict__ souts,
    const float* __restrict__ r_k, const float* __restrict__ vfirst,
    __bf16* __restrict__ ob, float* __restrict__ dout) {
    int t = blockIdx.x >> 5;
    int h = blockIdx.x & 31;
    int n = threadIdx.x;
    int idx = t * C_DIM + h * HEAD + n;
    float s = rbuf[idx] * kbuf[idx] * r_k[h * HEAD + n];
#pragma unroll
    for (int off = 32; off > 0; off >>= 1) s += __shfl_xor(s, off);
    float ov = souts[idx] + s * vbuf[idx];
    ob[idx] = (__bf16)ov;
    dout[BTC + idx] = vfirst[idx];
}

// ---------------- host launcher ----------------
extern "C" void kernel_launch(void* const* d_in, const int* in_sizes, int n_in,
                              void* d_out, int out_size, void* d_ws, size_t ws_size,
                              hipStream_t stream) {
    const float* x      = (const float*)d_in[0];
    const float* vfirst = (const float*)d_in[1];
    const float* amask  = (const float*)d_in[2];
    const float* w0 = (const float*)d_in[3];
    const float* w1 = (const float*)d_in[4];
    const float* w2 = (const float*)d_in[5];
    const float* a0 = (const float*)d_in[6];
    const float* a1 = (const float*)d_in[7];
    const float* a2 = (const float*)d_in[8];
    const float* v0 = (const float*)d_in[9];
    const float* v1 = (const float*)d_in[10];
    const float* v2 = (const float*)d_in[11];
    const float* k_k = (const float*)d_in[12];
    const float* k_a = (const float*)d_in[13];
    const float* r_k = (const float*)d_in[14];
    const float* Wr = (const float*)d_in[15];
    const float* Wk = (const float*)d_in[16];
    const float* Wv = (const float*)d_in[17];
    const float* Wo = (const float*)d_in[18];
    float* dout = (float*)d_out;

    char* wp = (char*)d_ws;
    auto alloc = [&](size_t bytes) -> void* {
        void* p = (void*)wp;
        wp += (bytes + 255) & ~(size_t)255;
        return p;
    };
    __bf16* xb  = (__bf16*)alloc((size_t)BTC * 2);
    __bf16* WrT = (__bf16*)alloc((size_t)C_DIM * C_DIM * 2);
    __bf16* WkT = (__bf16*)alloc((size_t)C_DIM * C_DIM * 2);
    __bf16* WvT = (__bf16*)alloc((size_t)C_DIM * C_DIM * 2);
    __bf16* WoT = (__bf16*)alloc((size_t)C_DIM * C_DIM * 2);
    __bf16* w1T = (__bf16*)alloc((size_t)96 * C_DIM * 2);
    __bf16* a1T = (__bf16*)alloc((size_t)96 * C_DIM * 2);
    __bf16* v1T = (__bf16*)alloc((size_t)64 * C_DIM * 2);
    __bf16* w2T = (__bf16*)alloc((size_t)C_DIM * 96 * 2);
    __bf16* a2T = (__bf16*)alloc((size_t)C_DIM * 96 * 2);
    __bf16* v2T = (__bf16*)alloc((size_t)C_DIM * 64 * 2);
    float*  rbuf = (float*)alloc((size_t)BTC * 4);
    float*  kbuf = (float*)alloc((size_t)BTC * 4);
    float*  vbuf = (float*)alloc((size_t)BTC * 4);
    float*  hw  = (float*)alloc((size_t)T_LEN * 96 * 4);
    float*  ha  = (float*)alloc((size_t)T_LEN * 96 * 4);
    float*  hv  = (float*)alloc((size_t)T_LEN * 64 * 4);
    __bf16* hwb = (__bf16*)alloc((size_t)T_LEN * 96 * 2);
    __bf16* hab = (__bf16*)alloc((size_t)T_LEN * 96 * 2);
    __bf16* hvb = (__bf16*)alloc((size_t)T_LEN * 64 * 2);
    float*  ywb = (float*)alloc((size_t)BTC * 4);   // -> d_eff
    float*  yab = (float*)alloc((size_t)BTC * 4);   // -> b_eff
    float*  yvb = (float*)alloc((size_t)BTC * 4);   // -> a_eff
    float*  sck = (float*)alloc((size_t)BTC * 4);   // k_eff
    float*  scv = (float*)alloc((size_t)BTC * 4);   // v_eff
    float*  souts = (float*)alloc((size_t)BTC * 4);
    __bf16* ob  = (__bf16*)alloc((size_t)BTC * 2);

    // 1) cast x -> bf16
    cast_bf16_k<<<dim3(BTC / 256), 256, 0, stream>>>(x, xb, BTC);

    // 2) transpose+cast all weights (dst = C x R)
    dim3 tb(32, 8);
    transpose_cast_k<<<dim3(64, 64), tb, 0, stream>>>(Wr, WrT, C_DIM, C_DIM);
    transpose_cast_k<<<dim3(64, 64), tb, 0, stream>>>(Wk, WkT, C_DIM, C_DIM);
    transpose_cast_k<<<dim3(64, 64), tb, 0, stream>>>(Wv, WvT, C_DIM, C_DIM);
    transpose_cast_k<<<dim3(64, 64), tb, 0, stream>>>(Wo, WoT, C_DIM, C_DIM);
    transpose_cast_k<<<dim3(3, 64), tb, 0, stream>>>(w1, w1T, C_DIM, 96);
    transpose_cast_k<<<dim3(3, 64), tb, 0, stream>>>(a1, a1T, C_DIM, 96);
    transpose_cast_k<<<dim3(2, 64), tb, 0, stream>>>(v1, v1T, C_DIM, 64);
    transpose_cast_k<<<dim3(64, 3), tb, 0, stream>>>(w2, w2T, 96, C_DIM);
    transpose_cast_k<<<dim3(64, 3), tb, 0, stream>>>(a2, a2T, 96, C_DIM);
    transpose_cast_k<<<dim3(64, 2), tb, 0, stream>>>(v2, v2T, 64, C_DIM);

    // 3) big GEMMs: r, k, v
    gemm_bt_16x64<<<dim3(16, 32), 256, 0, stream>>>(xb, WrT, rbuf, T_LEN, C_DIM, C_DIM);
    gemm_bt_16x64<<<dim3(16, 32), 256, 0, stream>>>(xb, WkT, kbuf, T_LEN, C_DIM, C_DIM);
    gemm_bt_16x64<<<dim3(16, 32), 256, 0, stream>>>(xb, WvT, vbuf, T_LEN, C_DIM, C_DIM);

    // 4) LoRA first stage
    gemm_bt_w16<<<dim3(64, 6), 64, 0, stream>>>(xb, w1T, hw, T_LEN, 96, C_DIM);
    gemm_bt_w16<<<dim3(64, 6), 64, 0, stream>>>(xb, a1T, ha, T_LEN, 96, C_DIM);
    gemm_bt_w16<<<dim3(64, 4), 64, 0, stream>>>(xb, v1T, hv, T_LEN, 64, C_DIM);

    // 5) activations + cast
    tanh_cast_k<<<dim3((T_LEN * 96 + 255) / 256), 256, 0, stream>>>(hw, hwb, T_LEN * 96);
    cast_bf16_k<<<dim3((T_LEN * 96 + 255) / 256), 256, 0, stream>>>(ha, hab, T_LEN * 96);
    cast_bf16_k<<<dim3((T_LEN * 64 + 255) / 256), 256, 0, stream>>>(hv, hvb, T_LEN * 64);

    // 6) LoRA second stage
    gemm_bt_w16<<<dim3(64, 128), 64, 0, stream>>>(hwb, w2T, ywb, T_LEN, C_DIM, 96);
    gemm_bt_w16<<<dim3(64, 128), 64, 0, stream>>>(hab, a2T, yab, T_LEN, C_DIM, 96);
    gemm_bt_w16<<<dim3(64, 128), 64, 0, stream>>>(hvb, v2T, yvb, T_LEN, C_DIM, 64);

    // 7) prep: decay, gates, kk-normalize, mask folding
    prep_k<<<dim3(T_LEN * H_N), 64, 0, stream>>>(kbuf, vbuf, vfirst, ywb, yab, yvb,
                                                 sck, scv, w0, a0, v0, k_k, k_a, amask);

    // 8) sequential scan: 256 blocks x 1 wave, no barriers
    scan_k<<<dim3(H_N * 8), 64, 0, stream>>>(ywb, yvb, yab, sck, scv, rbuf, souts);

    // 9) residual + cast + v_first passthrough
    resid_k<<<dim3(T_LEN * H_N), 64, 0, stream>>>(rbuf, kbuf, vbuf, souts, r_k, vfirst,
                                                  ob, dout);

    // 10) final GEMM: dout[0:BTC] = ob @ Wo
    gemm_bt_16x64<<<dim3(16, 32), 256, 0, stream>>>(ob, WoT, dout, T_LEN, C_DIM, C_DIM);
}

// Round 3
// 979.118 us; speedup vs baseline: 1.8046x; 1.0136x over previous
//
#include <hip/hip_runtime.h>
#include <math.h>

#define T_LEN 1024
#define C_DIM 2048
#define H_N   32
#define HEAD  64
#define BTC   (T_LEN * C_DIM)

typedef __attribute__((ext_vector_type(8))) __bf16 bf16x8;
typedef __attribute__((ext_vector_type(4))) float  f32x4;

// ---------------- elementwise cast kernels ----------------
__global__ void cast_bf16_k(const float* __restrict__ s, __bf16* __restrict__ d, int n) {
    int i = blockIdx.x * 256 + threadIdx.x;
    if (i < n) d[i] = (__bf16)s[i];
}
__global__ void tanh_cast_k(const float* __restrict__ s, __bf16* __restrict__ d, int n) {
    int i = blockIdx.x * 256 + threadIdx.x;
    if (i < n) d[i] = (__bf16)tanhf(s[i]);
}

// ---------------- transpose + cast: dst[c*R + r] = (bf16)src[r*C + c] ----------------
__global__ void transpose_cast_k(const float* __restrict__ src, __bf16* __restrict__ dst,
                                 int R, int C) {
    __shared__ float tile[32][33];
    int c0 = blockIdx.x * 32, r0 = blockIdx.y * 32;
    int tx = threadIdx.x, ty = threadIdx.y;
#pragma unroll
    for (int i = 0; i < 32; i += 8)
        tile[ty + i][tx] = src[(size_t)(r0 + ty + i) * C + c0 + tx];
    __syncthreads();
#pragma unroll
    for (int i = 0; i < 32; i += 8)
        dst[(size_t)(c0 + ty + i) * R + r0 + tx] = (__bf16)tile[tx][ty + i];
}

// ---------------- big GEMM: O(MxN) fp32 = A(MxK) bf16 * BT(NxK) bf16 ----------------
__global__ __launch_bounds__(256) void gemm_bt_16x64(
    const __bf16* __restrict__ A, const __bf16* __restrict__ BT,
    float* __restrict__ O, int M, int N, int K) {
    int lane = threadIdx.x & 63;
    int wv   = threadIdx.x >> 6;
    int m    = lane & 15;
    int q    = lane >> 4;
    int row0 = blockIdx.x * 64 + wv * 16;
    int col0 = blockIdx.y * 64;

    const __bf16* ap = A  + (size_t)(row0 + m) * K + q * 8;
    const __bf16* bp = BT + (size_t)(col0 + m) * K + q * 8;
    size_t bstride = (size_t)16 * K;

    f32x4 acc0 = {0.f,0.f,0.f,0.f}, acc1 = acc0, acc2 = acc0, acc3 = acc0;

    for (int k0 = 0; k0 < K; k0 += 32) {
        bf16x8 av = *(const bf16x8*)(ap + k0);
        bf16x8 b0 = *(const bf16x8*)(bp + k0);
        bf16x8 b1 = *(const bf16x8*)(bp + bstride + k0);
        bf16x8 b2 = *(const bf16x8*)(bp + 2 * bstride + k0);
        bf16x8 b3 = *(const bf16x8*)(bp + 3 * bstride + k0);
        acc0 = __builtin_amdgcn_mfma_f32_16x16x32_bf16(av, b0, acc0, 0, 0, 0);
        acc1 = __builtin_amdgcn_mfma_f32_16x16x32_bf16(av, b1, acc1, 0, 0, 0);
        acc2 = __builtin_amdgcn_mfma_f32_16x16x32_bf16(av, b2, acc2, 0, 0, 0);
        acc3 = __builtin_amdgcn_mfma_f32_16x16x32_bf16(av, b3, acc3, 0, 0, 0);
    }
    int orow = row0 + q * 4;
    int ocol = col0 + m;
#pragma unroll
    for (int i = 0; i < 4; i++) {
        O[(size_t)(orow + i) * N + ocol]      = acc0[i];
        O[(size_t)(orow + i) * N + ocol + 16] = acc1[i];
        O[(size_t)(orow + i) * N + ocol + 32] = acc2[i];
        O[(size_t)(orow + i) * N + ocol + 48] = acc3[i];
    }
}

// ---------------- small GEMM: one wave per 16x16 tile ----------------
__global__ __launch_bounds__(64) void gemm_bt_w16(
    const __bf16* __restrict__ A, const __bf16* __restrict__ BT,
    float* __restrict__ O, int M, int N, int K) {
    int lane = threadIdx.x & 63;
    int m = lane & 15, q = lane >> 4;
    int row0 = blockIdx.x * 16;
    int col0 = blockIdx.y * 16;
    const __bf16* ap = A  + (size_t)(row0 + m) * K + q * 8;
    const __bf16* bp = BT + (size_t)(col0 + m) * K + q * 8;
    f32x4 acc = {0.f,0.f,0.f,0.f};
    for (int k0 = 0; k0 < K; k0 += 32) {
        bf16x8 av = *(const bf16x8*)(ap + k0);
        bf16x8 bv = *(const bf16x8*)(bp + k0);
        acc = __builtin_amdgcn_mfma_f32_16x16x32_bf16(av, bv, acc, 0, 0, 0);
    }
    int orow = row0 + q * 4;
    int ocol = col0 + m;
#pragma unroll
    for (int i = 0; i < 4; i++)
        O[(size_t)(orow + i) * N + ocol] = acc[i];
}

// ---------------- prep: decay / gates / kk-normalize + mask folding ----------------
__global__ __launch_bounds__(64) void prep_k(
    float* __restrict__ kbuf, float* __restrict__ vbuf,
    const float* __restrict__ vfirst,
    float* __restrict__ ywb, float* __restrict__ yab, float* __restrict__ yvb,
    float* __restrict__ sck, float* __restrict__ scv,
    const float* __restrict__ w0, const float* __restrict__ a0,
    const float* __restrict__ v0, const float* __restrict__ k_k,
    const float* __restrict__ k_a, const float* __restrict__ amask) {
    int t = blockIdx.x >> 5;
    int h = blockIdx.x & 31;
    int n = threadIdx.x;
    int cc  = h * HEAD + n;
    int idx = t * C_DIM + cc;
    float m = amask[t];

    float kv = kbuf[idx];
    float vv = vbuf[idx];
    float wv = w0[cc] + ywb[idx];
    float wfin = -log1pf(expf(-wv)) - 0.6f;       // -softplus(-x) - 0.6
    float dec  = expf(-expf(wfin));
    float sv   = 1.f / (1.f + expf(-(v0[cc] + yvb[idx])));
    float vnew = fmaf(vfirst[idx] - vv, sv, vv);
    float av   = 1.f / (1.f + expf(-(a0[cc] + yab[idx])));
    float kkp  = kv * k_k[cc];
    float ss = kkp * kkp;
#pragma unroll
    for (int off = 32; off > 0; off >>= 1) ss += __shfl_xor(ss, off);
    float kkn  = kkp / fmaxf(sqrtf(ss), 1e-12f);
    float knew = kv * (1.f + (av - 1.f) * k_a[cc]);

    ywb[idx]  = dec * m + (1.f - m);   // d_eff
    yvb[idx]  = -kkn * m;              // a_eff
    yab[idx]  = kkn * av * m;          // b_eff
    sck[idx]  = knew * m;              // k_eff
    scv[idx]  = vnew * m;              // v_eff
    kbuf[idx] = knew;                  // unmasked, for residual
    vbuf[idx] = vnew;                  // unmasked, for residual
}

// ---------------- sequential scan: 256 single-wave blocks, depth-2 pipeline ----------------
// block = (head h, row-group g). lane = (r<<3)|c: lane holds S[g*8+r][c*8..c*8+8).
// XCD swizzle: all 8 row-groups of a head share blockIdx%8 -> same XCD L2.
struct StepRegs { float d[8], a[8], b[8], k[8], r[8]; float v; };

__device__ __forceinline__ void load_step(StepRegs& s,
    const float* __restrict__ dm, const float* __restrict__ am,
    const float* __restrict__ bm, const float* __restrict__ km,
    const float* __restrict__ vm, const float* __restrict__ rm,
    int off, int jb, int row) {
    *(float4*)&s.d[0] = *(const float4*)(dm + off + jb);
    *(float4*)&s.d[4] = *(const float4*)(dm + off + jb + 4);
    *(float4*)&s.a[0] = *(const float4*)(am + off + jb);
    *(float4*)&s.a[4] = *(const float4*)(am + off + jb + 4);
    *(float4*)&s.b[0] = *(const float4*)(bm + off + jb);
    *(float4*)&s.b[4] = *(const float4*)(bm + off + jb + 4);
    *(float4*)&s.k[0] = *(const float4*)(km + off + jb);
    *(float4*)&s.k[4] = *(const float4*)(km + off + jb + 4);
    *(float4*)&s.r[0] = *(const float4*)(rm + off + jb);
    *(float4*)&s.r[4] = *(const float4*)(rm + off + jb + 4);
    s.v = vm[off + row];
}

__global__ __launch_bounds__(64) void scan_k(
    const float* __restrict__ dm, const float* __restrict__ am,
    const float* __restrict__ bm, const float* __restrict__ km,
    const float* __restrict__ vm, const float* __restrict__ rm,
    float* __restrict__ out) {
    // swizzle: b = xcd + 8*(hi + 4*g), h = xcd + 8*hi, g = row-group
    int b = blockIdx.x;
    int xcd  = b & 7;
    int rest = b >> 3;
    int hi   = rest & 3;
    int g    = rest >> 2;
    int h    = xcd + 8 * hi;

    int lane = threadIdx.x;
    int r = lane >> 3;
    int c = lane & 7;
    int row = g * 8 + r;
    int jb  = c * 8;

    float S[8];
#pragma unroll
    for (int j = 0; j < 8; j++) S[j] = 0.f;

    int hoff = h * HEAD;
    StepRegs A, B;
    load_step(A, dm, am, bm, km, vm, rm, hoff, jb, row);
    load_step(B, dm, am, bm, km, vm, rm, hoff + C_DIM, jb, row);

    auto compute = [&](StepRegs& s, int off) {
        // sa partial with split chains
        float p0 = 0.f, p1 = 0.f;
#pragma unroll
        for (int j = 0; j < 4; j++) {
            p0 = fmaf(S[j],     s.a[j],     p0);
            p1 = fmaf(S[j + 4], s.a[j + 4], p1);
        }
        float p = p0 + p1;
        p += __shfl_xor(p, 1);
        p += __shfl_xor(p, 2);
        p += __shfl_xor(p, 4);
        float sa = p;

        float o0 = 0.f, o1 = 0.f;
#pragma unroll
        for (int j = 0; j < 4; j++) {
            float s0 = fmaf(s.d[j], S[j], fmaf(sa, s.b[j], s.v * s.k[j]));
            S[j] = s0;
            o0 = fmaf(s0, s.r[j], o0);
            float s1 = fmaf(s.d[j + 4], S[j + 4], fmaf(sa, s.b[j + 4], s.v * s.k[j + 4]));
            S[j + 4] = s1;
            o1 = fmaf(s1, s.r[j + 4], o1);
        }
        float op = o0 + o1;
        op += __shfl_xor(op, 1);
        op += __shfl_xor(op, 2);
        op += __shfl_xor(op, 4);
        if (c == 0) out[off + row] = op;
    };

    int off = hoff;
    // main loop: t = 0..1021 in pairs; prefetch distance 2
    for (int t = 0; t < T_LEN - 2; t += 2) {
        compute(A, off);
        load_step(A, dm, am, bm, km, vm, rm, off + 2 * C_DIM, jb, row);
        compute(B, off + C_DIM);
        load_step(B, dm, am, bm, km, vm, rm, off + 3 * C_DIM, jb, row);
        off += 2 * C_DIM;
    }
    compute(A, off);
    compute(B, off + C_DIM);
}

// ---------------- residual + cast + v_first passthrough ----------------
__global__ __launch_bounds__(64) void resid_k(
    const float* __restrict__ rbuf, const float* __restrict__ kbuf,
    const float* __restrict__ vbuf, const float* __restrict__ souts,
    const float* __restrict__ r_k, const float* __restrict__ vfirst,
    __bf16* __restrict__ ob, float* __restrict__ dout) {
    int t = blockIdx.x >> 5;
    int h = blockIdx.x & 31;
    int n = threadIdx.x;
    int idx = t * C_DIM + h * HEAD + n;
    float s = rbuf[idx] * kbuf[idx] * r_k[h * HEAD + n];
#pragma unroll
    for (int off = 32; off > 0; off >>= 1) s += __shfl_xor(s, off);
    float ov = souts[idx] + s * vbuf[idx];
    ob[idx] = (__bf16)ov;
    dout[BTC + idx] = vfirst[idx];
}

// ---------------- host launcher ----------------
extern "C" void kernel_launch(void* const* d_in, const int* in_sizes, int n_in,
                              void* d_out, int out_size, void* d_ws, size_t ws_size,
                              hipStream_t stream) {
    const float* x      = (const float*)d_in[0];
    const float* vfirst = (const float*)d_in[1];
    const float* amask  = (const float*)d_in[2];
    const float* w0 = (const float*)d_in[3];
    const float* w1 = (const float*)d_in[4];
    const float* w2 = (const float*)d_in[5];
    const float* a0 = (const float*)d_in[6];
    const float* a1 = (const float*)d_in[7];
    const float* a2 = (const float*)d_in[8];
    const float* v0 = (const float*)d_in[9];
    const float* v1 = (const float*)d_in[10];
    const float* v2 = (const float*)d_in[11];
    const float* k_k = (const float*)d_in[12];
    const float* k_a = (const float*)d_in[13];
    const float* r_k = (const float*)d_in[14];
    const float* Wr = (const float*)d_in[15];
    const float* Wk = (const float*)d_in[16];
    const float* Wv = (const float*)d_in[17];
    const float* Wo = (const float*)d_in[18];
    float* dout = (float*)d_out;

    char* wp = (char*)d_ws;
    auto alloc = [&](size_t bytes) -> void* {
        void* p = (void*)wp;
        wp += (bytes + 255) & ~(size_t)255;
        return p;
    };
    __bf16* xb  = (__bf16*)alloc((size_t)BTC * 2);
    __bf16* WrT = (__bf16*)alloc((size_t)C_DIM * C_DIM * 2);
    __bf16* WkT = (__bf16*)alloc((size_t)C_DIM * C_DIM * 2);
    __bf16* WvT = (__bf16*)alloc((size_t)C_DIM * C_DIM * 2);
    __bf16* WoT = (__bf16*)alloc((size_t)C_DIM * C_DIM * 2);
    __bf16* w1T = (__bf16*)alloc((size_t)96 * C_DIM * 2);
    __bf16* a1T = (__bf16*)alloc((size_t)96 * C_DIM * 2);
    __bf16* v1T = (__bf16*)alloc((size_t)64 * C_DIM * 2);
    __bf16* w2T = (__bf16*)alloc((size_t)C_DIM * 96 * 2);
    __bf16* a2T = (__bf16*)alloc((size_t)C_DIM * 96 * 2);
    __bf16* v2T = (__bf16*)alloc((size_t)C_DIM * 64 * 2);
    float*  rbuf = (float*)alloc((size_t)BTC * 4);
    float*  kbuf = (float*)alloc((size_t)BTC * 4);
    float*  vbuf = (float*)alloc((size_t)BTC * 4);
    float*  hw  = (float*)alloc((size_t)T_LEN * 96 * 4);
    float*  ha  = (float*)alloc((size_t)T_LEN * 96 * 4);
    float*  hv  = (float*)alloc((size_t)T_LEN * 64 * 4);
    __bf16* hwb = (__bf16*)alloc((size_t)T_LEN * 96 * 2);
    __bf16* hab = (__bf16*)alloc((size_t)T_LEN * 96 * 2);
    __bf16* hvb = (__bf16*)alloc((size_t)T_LEN * 64 * 2);
    float*  ywb = (float*)alloc((size_t)BTC * 4);   // -> d_eff
    float*  yab = (float*)alloc((size_t)BTC * 4);   // -> b_eff
    float*  yvb = (float*)alloc((size_t)BTC * 4);   // -> a_eff
    float*  sck = (float*)alloc((size_t)BTC * 4);   // k_eff
    float*  scv = (float*)alloc((size_t)BTC * 4);   // v_eff
    float*  souts = (float*)alloc((size_t)BTC * 4);
    __bf16* ob  = (__bf16*)alloc((size_t)BTC * 2);

    // 1) cast x -> bf16
    cast_bf16_k<<<dim3(BTC / 256), 256, 0, stream>>>(x, xb, BTC);

    // 2) transpose+cast all weights (dst = C x R)
    dim3 tb(32, 8);
    transpose_cast_k<<<dim3(64, 64), tb, 0, stream>>>(Wr, WrT, C_DIM, C_DIM);
    transpose_cast_k<<<dim3(64, 64), tb, 0, stream>>>(Wk, WkT, C_DIM, C_DIM);
    transpose_cast_k<<<dim3(64, 64), tb, 0, stream>>>(Wv, WvT, C_DIM, C_DIM);
    transpose_cast_k<<<dim3(64, 64), tb, 0, stream>>>(Wo, WoT, C_DIM, C_DIM);
    transpose_cast_k<<<dim3(3, 64), tb, 0, stream>>>(w1, w1T, C_DIM, 96);
    transpose_cast_k<<<dim3(3, 64), tb, 0, stream>>>(a1, a1T, C_DIM, 96);
    transpose_cast_k<<<dim3(2, 64), tb, 0, stream>>>(v1, v1T, C_DIM, 64);
    transpose_cast_k<<<dim3(64, 3), tb, 0, stream>>>(w2, w2T, 96, C_DIM);
    transpose_cast_k<<<dim3(64, 3), tb, 0, stream>>>(a2, a2T, 96, C_DIM);
    transpose_cast_k<<<dim3(64, 2), tb, 0, stream>>>(v2, v2T, 64, C_DIM);

    // 3) big GEMMs: r, k, v
    gemm_bt_16x64<<<dim3(16, 32), 256, 0, stream>>>(xb, WrT, rbuf, T_LEN, C_DIM, C_DIM);
    gemm_bt_16x64<<<dim3(16, 32), 256, 0, stream>>>(xb, WkT, kbuf, T_LEN, C_DIM, C_DIM);
    gemm_bt_16x64<<<dim3(16, 32), 256, 0, stream>>>(xb, WvT, vbuf, T_LEN, C_DIM, C_DIM);

    // 4) LoRA first stage
    gemm_bt_w16<<<dim3(64, 6), 64, 0, stream>>>(xb, w1T, hw, T_LEN, 96, C_DIM);
    gemm_bt_w16<<<dim3(64, 6), 64, 0, stream>>>(xb, a1T, ha, T_LEN, 96, C_DIM);
    gemm_bt_w16<<<dim3(64, 4), 64, 0, stream>>>(xb, v1T, hv, T_LEN, 64, C_DIM);

    // 5) activations + cast
    tanh_cast_k<<<dim3((T_LEN * 96 + 255) / 256), 256, 0, stream>>>(hw, hwb, T_LEN * 96);
    cast_bf16_k<<<dim3((T_LEN * 96 + 255) / 256), 256, 0, stream>>>(ha, hab, T_LEN * 96);
    cast_bf16_k<<<dim3((T_LEN * 64 + 255) / 256), 256, 0, stream>>>(hv, hvb, T_LEN * 64);

    // 6) LoRA second stage
    gemm_bt_w16<<<dim3(64, 128), 64, 0, stream>>>(hwb, w2T, ywb, T_LEN, C_DIM, 96);
    gemm_bt_w16<<<dim3(64, 128), 64, 0, stream>>>(hab, a2T, yab, T_LEN, C_DIM, 96);
    gemm_bt_w16<<<dim3(64, 128), 64, 0, stream>>>(hvb, v2T, yvb, T_LEN, C_DIM, 64);

    // 7) prep: decay, gates, kk-normalize, mask folding
    prep_k<<<dim3(T_LEN * H_N), 64, 0, stream>>>(kbuf, vbuf, vfirst, ywb, yab, yvb,
                                                 sck, scv, w0, a0, v0, k_k, k_a, amask);

    // 8) sequential scan: 256 blocks x 1 wave, depth-2 pipeline, XCD swizzle
    scan_k<<<dim3(H_N * 8), 64, 0, stream>>>(ywb, yvb, yab, sck, scv, rbuf, souts);

    // 9) residual + cast + v_first passthrough
    resid_k<<<dim3(T_LEN * H_N), 64, 0, stream>>>(rbuf, kbuf, vbuf, souts, r_k, vfirst,
                                                  ob, dout);

    // 10) final GEMM: dout[0:BTC] = ob @ Wo
    gemm_bt_16x64<<<dim3(16, 32), 256, 0, stream>>>(ob, WoT, dout, T_LEN, C_DIM, C_DIM);
}